// Round 6
// baseline (195.294 us; speedup 1.0000x reference)
//
#include <hip/hip_runtime.h>
#include <hip/hip_bf16.h>

#define T_DIM 800
#define B_DIM 32
#define V_DIM 1024
#define S_DIM 100
#define L2E  1.4426950408889634f
#define LN2  0.6931471805599453f

#define CHUNK 48
#define ROWW  104
#define ENTRIES (CHUNK*ROWW)     /* 4992 */
#define LTHREADS 192
#define LPER 26                  /* 4992/192 exact */

#define NRED 1504
#define GRID_TOT (B_DIM + NRED)
#define BLK 256

// ws layout (32-bit slots):
// [0]                  : uint counter (zeroed by hipMemsetAsync each call)
// [1 .. 1+NRED)        : float partial sums (smoothing reduction)
// [1+NRED .. 1+NRED+32): float per-batch nll

__device__ __forceinline__ void combine(int l, const float* partials, const float* nlls,
                                        const int* tlen, float* out)
{
    float ps = 0.0f;
    for (int i = l; i < NRED; i += 64) ps += partials[i];
    for (int off = 32; off; off >>= 1) ps += __shfl_down(ps, off, 64);
    float cs = 0.0f;
    if (l < B_DIM) cs = nlls[l] / (float)tlen[l];
    for (int off = 32; off; off >>= 1) cs += __shfl_down(cs, off, 64);
    if (l == 0) {
        float smooth = -ps / (float)((long long)T_DIM * B_DIM * V_DIM);
        float ctc = cs / (float)B_DIM;
        out[0] = 0.9f * ctc + 0.1f * smooth;
    }
}

extern "C" __global__ void __launch_bounds__(BLK)
ctc_main(const float* __restrict__ lp,
         const int* __restrict__ tgt,
         const int* __restrict__ ilen,
         const int* __restrict__ tlen,
         float* __restrict__ ws,
         float* __restrict__ out)
{
    __shared__ float buf[2][ENTRIES];
    __shared__ float ebS[2][CHUNK];
    __shared__ int   tgtS[S_DIM];
    __shared__ float red[BLK / 64];

    unsigned int* cnt = (unsigned int*)ws;
    float* partials = ws + 1;
    float* nlls = ws + 1 + NRED;
    const int bid = blockIdx.x;
    const int tid = threadIdx.x;

    if (bid < B_DIM) {
        const int b = bid;
        const int len = ilen[b];      // uniform in block
        const int tl  = tlen[b];
        const int wav = tid >> 6;
        const int l   = tid & 63;

        const int steps_total = len - 1;                 // t = 1 .. len-1
        const int NCfull = steps_total / CHUNK;
        const int tail   = steps_total - NCfull * CHUNK;
        const int NC     = NCfull + (tail ? 1 : 0);

        if (tid >= 64 && tid < 64 + S_DIM) tgtS[tid - 64] = tgt[b * S_DIM + (tid - 64)];
        __syncthreads();   // A: tgtS ready

        // ---------------- consumer state ----------------
        // lane l owns extended states 4l..4l+3 as linear probs p0..p3,
        // true alpha = p * 2^el.  qv = left lane's n3 (alpha[4l-1]) shuffled
        // each step; scale converted via sfg (in-group) / sff (group boundary).
        float p0 = 0, p1 = 0, p2 = 0, p3 = 0;
        float qv = 0, sff = 0, sfg = 0;
        int   el = 0, eLp = 0;
        float cs1f = 0, cs3f = 0;
        int   off1 = 101;
        float ebg[2][4], e1g[2][4], e3g[2][4];
        // loader state
        int woffs[LPER], doffs[LPER];
        unsigned zbits = 0, ebits = 0;

        if (wav == 0) {
            __builtin_amdgcn_s_setprio(1);
            int v1 = 0;
            if (l <= 49) {
                v1 = tgtS[2 * l];
                int vp = (l >= 1) ? tgtS[2 * l - 1] : -1;
                cs1f = (v1 != vp) ? 1.0f : 0.0f;
                int v3 = tgtS[2 * l + 1];
                cs3f = (v3 != v1) ? 1.0f : 0.0f;
                off1 = 2 * l + 1;
            }
            // t = 0 init (linear domain, frame el = 0)
            float eb0 = lp[b * V_DIM];
            float e10 = lp[b * V_DIM + v1];
            p0 = (l == 0) ? __builtin_amdgcn_exp2f(eb0 * L2E) : 0.0f;
            p1 = (l == 0) ? __builtin_amdgcn_exp2f(e10 * L2E) : 0.0f;
        } else {
            const int j = tid - 64;   // 0..191
            #pragma unroll
            for (int u = 0; u < LPER; ++u) {
                int i = j + u * LTHREADS;                     // 0..4991
                int tt = (int)(((long long)i * 40330) >> 22); // i / 104
                int k  = i - tt * ROWW;
                int v  = (k >= 1 && k <= 100) ? tgtS[k - 1] : 0;
                woffs[u] = tt * (B_DIM * V_DIM) + v;
                doffs[u] = tt * ROWW + k;
                if (k <= 100) zbits |= (1u << u);
                if (k == 0)   ebits |= (1u << u);
            }
        }

#define STAGE_FAST(PAR, TB) do { \
    const float* src_ = lp + (size_t)(TB) * (B_DIM * V_DIM) + b * V_DIM; \
    float* dst_ = buf[PAR]; float* ebd_ = ebS[PAR]; \
    _Pragma("unroll") \
    for (int u = 0; u < LPER; ++u) { \
        float val_ = src_[woffs[u]]; \
        float v2_ = ((zbits >> u) & 1u) ? __builtin_amdgcn_exp2f(val_ * L2E) : 0.0f; \
        dst_[doffs[u]] = v2_; \
        if ((ebits >> u) & 1u) { \
            int tt_ = (int)(((long long)doffs[u] * 40330) >> 22); \
            ebd_[tt_] = v2_; \
        } \
    } \
} while (0)

#define STAGE_SLOW(PAR, TB) do { \
    const int j_ = tid - 64; \
    float* dst_ = buf[PAR]; float* ebd_ = ebS[PAR]; \
    _Pragma("unroll") \
    for (int u = 0; u < LPER; ++u) { \
        int i_ = j_ + u * LTHREADS; \
        int tt_ = (int)(((long long)i_ * 40330) >> 22); \
        int k_  = i_ - tt_ * ROWW; \
        int t_  = (TB) + tt_; t_ = (t_ > T_DIM - 1) ? (T_DIM - 1) : t_; \
        int v_  = (k_ >= 1 && k_ <= 100) ? tgtS[k_ - 1] : 0; \
        float val_ = lp[((size_t)t_ * B_DIM + b) * V_DIM + v_]; \
        float v2_ = (k_ <= 100) ? __builtin_amdgcn_exp2f(val_ * L2E) : 0.0f; \
        dst_[tt_ * ROWW + k_] = v2_; \
        if (k_ == 0) ebd_[tt_] = v2_; \
    } \
} while (0)

        if (wav != 0) STAGE_FAST(0, 1);    // stage chunk 0
        __syncthreads();   // B: buf0 ready

        // ------------- consumer macros -------------
#define PREF(bk, GG) do { \
    const float* rr_ = bufc + (GG) * (4 * ROWW) + off1; \
    e1g[bk][0] = rr_[0];          e3g[bk][0] = rr_[1]; \
    e1g[bk][1] = rr_[ROWW];       e3g[bk][1] = rr_[ROWW + 1]; \
    e1g[bk][2] = rr_[2 * ROWW];   e3g[bk][2] = rr_[2 * ROWW + 1]; \
    e1g[bk][3] = rr_[3 * ROWW];   e3g[bk][3] = rr_[3 * ROWW + 1]; \
    const float4 u_ = *(const float4*)(ebc + (GG) * 4); \
    ebg[bk][0] = u_.x; ebg[bk][1] = u_.y; ebg[bk][2] = u_.z; ebg[bk][3] = u_.w; \
} while (0)

// renorm lane max to [1,2); 2-level dead-lane exponent adoption; build scale
// factors from POST-adoption left exponent (3 shuffles — the R5 bug was
// reading the PRE-adoption left exponent, misscaling dead->dead crossings).
#define BD do { \
    float mz_ = fmaxf(fmaxf(p0, p1), fmaxf(p2, p3)); \
    int dead_ = (mz_ == 0.0f) ? 1 : 0; \
    int er_ = (int)((__float_as_uint(mz_) >> 23) & 255u); \
    unsigned fld_ = dead_ ? 127u : (unsigned)(254 - er_); \
    float sc_ = __uint_as_float(fld_ << 23); \
    p0 *= sc_; p1 *= sc_; p2 *= sc_; p3 *= sc_; \
    el += dead_ ? 0 : (er_ - 127); \
    int e1s_ = __shfl_up(el, 1, 64); \
    int elA_ = dead_ ? e1s_ : el; \
    int e2s_ = __shfl_up(elA_, 1, 64); \
    int elB_ = dead_ ? e2s_ : el; \
    int e3s_ = __shfl_up(elB_, 1, 64); \
    int d1_ = e3s_ - elB_; d1_ = d1_ < -120 ? -120 : (d1_ > 120 ? 120 : d1_); \
    int d2_ = eLp  - elB_; d2_ = d2_ < -120 ? -120 : (d2_ > 120 ? 120 : d2_); \
    sfg = (l == 0) ? 0.0f : __uint_as_float((unsigned)(d1_ + 127) << 23); \
    sff = (l == 0) ? 0.0f : __uint_as_float((unsigned)(d2_ + 127) << 23); \
    el = elB_; eLp = e3s_; \
} while (0)

#define ST(SF, EB, E1, E3) do { \
    float h3_ = qv * (SF); \
    float vown_ = fmaf(cs3f, p1, p2 + p3); \
    float n3_ = vown_ * (E3); \
    float n0_ = (p0 + h3_) * (EB); \
    float n1_ = fmaf(cs1f, h3_, p0 + p1) * (E1); \
    float n2_ = (p1 + p2) * (EB); \
    qv = __shfl_up(n3_, 1, 64); \
    p0 = n0_; p1 = n1_; p2 = n2_; p3 = n3_; \
} while (0)

#define GRP(bk) do { \
    BD; \
    ST(sff, ebg[bk][0], e1g[bk][0], e3g[bk][0]); \
    ST(sfg, ebg[bk][1], e1g[bk][1], e3g[bk][1]); \
    ST(sfg, ebg[bk][2], e1g[bk][2], e3g[bk][2]); \
    ST(sfg, ebg[bk][3], e1g[bk][3], e3g[bk][3]); \
} while (0)

#define GRPT(bk, BASE) do { \
    if ((BASE) < nst) { \
        BD; \
        ST(sff, ebg[bk][0], e1g[bk][0], e3g[bk][0]); \
        if ((BASE) + 1 < nst) ST(sfg, ebg[bk][1], e1g[bk][1], e3g[bk][1]); \
        if ((BASE) + 2 < nst) ST(sfg, ebg[bk][2], e1g[bk][2], e3g[bk][2]); \
        if ((BASE) + 3 < nst) ST(sfg, ebg[bk][3], e1g[bk][3], e3g[bk][3]); \
    } \
} while (0)

        for (int c = 0; c < NC; ++c) {
            if (wav == 0) {
                const float* bufc = buf[c & 1];
                const float* ebc  = ebS[c & 1];
                if (c < NCfull) {
                    PREF(0, 0); PREF(1, 1);
                    for (int gp = 0; gp < 5; ++gp) {
                        GRP(0); PREF(0, 2 * gp + 2);
                        GRP(1); PREF(1, 2 * gp + 3);
                    }
                    GRP(0); GRP(1);
                } else {
                    const int nst = tail;
                    PREF(0, 0); PREF(1, 1);
                    for (int gp = 0; gp < 5; ++gp) {
                        GRPT(0, 8 * gp);     PREF(0, 2 * gp + 2);
                        GRPT(1, 8 * gp + 4); PREF(1, 2 * gp + 3);
                    }
                    GRPT(0, 40); GRPT(1, 44);
                }
            } else if (c + 1 < NC) {
                const int cc = c + 1;
                const int tb = 1 + cc * CHUNK;
                if (tb + CHUNK <= T_DIM) {
                    if (cc & 1) STAGE_FAST(1, tb); else STAGE_FAST(0, tb);
                } else {
                    if (cc & 1) STAGE_SLOW(1, tb); else STAGE_SLOW(0, tb);
                }
            }
            __syncthreads();
        }

        if (wav == 0) {
            // extract alpha[2*tl] and alpha[2*tl-1]  (log2 domain via p, el)
            int idx = 2 * tl;
            int lanehi = idx >> 2, rhi = idx & 3;
            int lanelo = (idx - 1) >> 2, rlo = (idx - 1) & 3;
            float q0 = __shfl(p0, lanehi, 64), q1 = __shfl(p1, lanehi, 64);
            float q2 = __shfl(p2, lanehi, 64), q3 = __shfl(p3, lanehi, 64);
            int   eh = __shfl(el, lanehi, 64);
            float ph = (rhi == 0) ? q0 : (rhi == 1) ? q1 : (rhi == 2) ? q2 : q3;
            float g0 = __shfl(p0, lanelo, 64), g1 = __shfl(p1, lanelo, 64);
            float g2 = __shfl(p2, lanelo, 64), g3 = __shfl(p3, lanelo, 64);
            int   eo = __shfl(el, lanelo, 64);
            float pl = (rlo == 0) ? g0 : (rlo == 1) ? g1 : (rlo == 2) ? g2 : g3;
            float vhi = (ph > 0.0f) ? __builtin_amdgcn_logf(ph) + (float)eh : -3.0e9f;
            float vlo = (pl > 0.0f) ? __builtin_amdgcn_logf(pl) + (float)eo : -3.0e9f;
            float m = fmaxf(vhi, vlo);
            float d = fminf(vhi, vlo) - m;
            float ll2 = m + __builtin_amdgcn_logf(1.0f + __builtin_amdgcn_exp2f(d));
            float nll = -ll2 * LN2;
            if (!(nll < 1e9f)) nll = 0.0f;   // zero_infinity (NaN-safe)

            int last = 0;
            if (l == 0) {
                nlls[b] = nll;
                __threadfence();
                unsigned old = __hip_atomic_fetch_add(cnt, 1u, __ATOMIC_ACQ_REL,
                                                      __HIP_MEMORY_SCOPE_AGENT);
                last = (old == GRID_TOT - 1) ? 1 : 0;
            }
            last = __shfl(last, 0, 64);
            if (last) combine(l, partials, nlls, tlen, out);
        }
        return;
    }

    // ---------------- label-smoothing sum: grid-stride float4 reduction ----------------
    const int rb = bid - B_DIM;
    const float4* lp4 = (const float4*)lp;
    const int n4 = (T_DIM * B_DIM * V_DIM) / 4;
    const int NT = NRED * BLK;
    float s = 0.0f;
    for (int i = rb * BLK + tid; i < n4; i += NT) {
        float4 v = lp4[i];
        s += (v.x + v.y) + (v.z + v.w);
    }
    for (int off = 32; off; off >>= 1) s += __shfl_down(s, off, 64);
    if ((tid & 63) == 0) red[tid >> 6] = s;
    __syncthreads();
    int last = 0;
    if (tid == 0) {
        float total = (red[0] + red[1]) + (red[2] + red[3]);
        partials[rb] = total;
        __threadfence();
        unsigned old = __hip_atomic_fetch_add(cnt, 1u, __ATOMIC_ACQ_REL,
                                              __HIP_MEMORY_SCOPE_AGENT);
        last = (old == GRID_TOT - 1) ? 1 : 0;
    }
    if (tid < 64) {
        last = __shfl(last, 0, 64);
        if (last) combine(tid, partials, nlls, tlen, out);
    }
}

extern "C" void kernel_launch(void* const* d_in, const int* in_sizes, int n_in,
                              void* d_out, int out_size, void* d_ws, size_t ws_size,
                              hipStream_t stream) {
    const float* lp  = (const float*)d_in[0];
    const int* tgt   = (const int*)d_in[1];
    const int* ilen  = (const int*)d_in[2];
    const int* tlen  = (const int*)d_in[3];
    float* out = (float*)d_out;
    float* ws  = (float*)d_ws;
    hipMemsetAsync(d_ws, 0, 4, stream);
    ctc_main<<<GRID_TOT, BLK, 0, stream>>>(lp, tgt, ilen, tlen, ws, out);
}

// Round 7
// 142.024 us; speedup vs baseline: 1.3751x; 1.3751x over previous
//
#include <hip/hip_runtime.h>
#include <hip/hip_bf16.h>

#define T_DIM 800
#define B_DIM 32
#define V_DIM 1024
#define S_DIM 100
#define L2E  1.4426950408889634f
#define LN2  0.6931471805599453f

#define CHUNK 48
#define ROWW  104
#define ENTRIES (CHUNK*ROWW)     /* 4992 */
#define BLK 512
#define LTHREADS (BLK - 64)      /* 448 loader threads */
#define LPER 12                  /* ceil(4992/448) */

#define NRED 752
#define GRID_TOT (B_DIM + NRED)

// ws layout (32-bit slots):
// [0]                  : uint counter (zeroed by hipMemsetAsync each call)
// [1 .. 1+NRED)        : float partial sums (smoothing reduction)
// [1+NRED .. 1+NRED+32): float per-batch nll

// DPP wave_shr1: whole-wave lane shift by 1 (lane l gets lane l-1; lane 0 gets old=0).
// VALU-latency cross-lane — replaces ds_permute-based __shfl_up on the critical path.
__device__ __forceinline__ float dpp_shr1_f(float x) {
    return __int_as_float(__builtin_amdgcn_update_dpp(
        0, __float_as_int(x), 0x138, 0xF, 0xF, false));
}
__device__ __forceinline__ int dpp_shr1_i(int x) {
    return __builtin_amdgcn_update_dpp(0, x, 0x138, 0xF, 0xF, false);
}

__device__ __forceinline__ void combine(int l, const float* partials, const float* nlls,
                                        const int* tlen, float* out)
{
    float ps = 0.0f;
    for (int i = l; i < NRED; i += 64) ps += partials[i];
    for (int off = 32; off; off >>= 1) ps += __shfl_down(ps, off, 64);
    float cs = 0.0f;
    if (l < B_DIM) cs = nlls[l] / (float)tlen[l];
    for (int off = 32; off; off >>= 1) cs += __shfl_down(cs, off, 64);
    if (l == 0) {
        float smooth = -ps / (float)((long long)T_DIM * B_DIM * V_DIM);
        float ctc = cs / (float)B_DIM;
        out[0] = 0.9f * ctc + 0.1f * smooth;
    }
}

extern "C" __global__ void __launch_bounds__(BLK, 4)
ctc_main(const float* __restrict__ lp,
         const int* __restrict__ tgt,
         const int* __restrict__ ilen,
         const int* __restrict__ tlen,
         float* __restrict__ ws,
         float* __restrict__ out)
{
    __shared__ float buf[2][ENTRIES];
    __shared__ __align__(16) float ebS[2][CHUNK];
    __shared__ int   tgtS[S_DIM];
    __shared__ float red[BLK / 64];

    unsigned int* cnt = (unsigned int*)ws;
    float* partials = ws + 1;
    float* nlls = ws + 1 + NRED;
    const int bid = blockIdx.x;
    const int tid = threadIdx.x;

    if (bid < B_DIM) {
        const int b = bid;
        const int len = ilen[b];      // uniform in block
        const int tl  = tlen[b];
        const int wav = tid >> 6;
        const int l   = tid & 63;

        const int steps_total = len - 1;                 // t = 1 .. len-1
        const int NCfull = steps_total / CHUNK;
        const int tail   = steps_total - NCfull * CHUNK;
        const int NC     = NCfull + (tail ? 1 : 0);

        if (tid >= 64 && tid < 64 + S_DIM) tgtS[tid - 64] = tgt[b * S_DIM + (tid - 64)];
        __syncthreads();   // A: tgtS ready

        // ---------------- consumer state ----------------
        // lane l owns extended states 4l..4l+3 as linear probs p0..p3,
        // true alpha = p * 2^el.  qv = left lane's n3 (alpha[4l-1]) shifted in
        // each step via DPP; scale converted via sfg (in-group) / sff (boundary).
        float p0 = 0, p1 = 0, p2 = 0, p3 = 0;
        float qv = 0, sff = 0, sfg = 0;
        int   el = 0, eLp = 0;
        float cs1f = 0, cs3f = 0;
        int   offE = 100;
        float ebg[2][4], e1g[2][4], e3g[2][4];
        // loader state
        int woffs[LPER], doffs[LPER], tts[LPER];
        unsigned zbits = 0, ebits = 0;

        if (wav == 0) {
            __builtin_amdgcn_s_setprio(1);
            int v1 = 0;
            if (l <= 49) {
                v1 = tgtS[2 * l];
                int vp = (l >= 1) ? tgtS[2 * l - 1] : -1;
                cs1f = (v1 != vp) ? 1.0f : 0.0f;
                int v3 = tgtS[2 * l + 1];
                cs3f = (v3 != v1) ? 1.0f : 0.0f;
                offE = 2 * l;
            }
            // t = 0 init (linear domain, frame el = 0)
            float eb0 = lp[b * V_DIM];
            float e10 = lp[b * V_DIM + v1];
            p0 = (l == 0) ? __builtin_amdgcn_exp2f(eb0 * L2E) : 0.0f;
            p1 = (l == 0) ? __builtin_amdgcn_exp2f(e10 * L2E) : 0.0f;
        } else {
            const int j = tid - 64;   // 0..447
            #pragma unroll
            for (int u = 0; u < LPER; ++u) {
                int i = j + u * LTHREADS; if (i > ENTRIES - 1) i = ENTRIES - 1;
                int tt = (int)(((long long)i * 40330) >> 22); // i / 104
                int k  = i - tt * ROWW;
                int v  = (k <= 99) ? tgtS[k] : 0;             // labels at k=0..99
                woffs[u] = tt * (B_DIM * V_DIM) + v;
                doffs[u] = i;
                tts[u]   = tt;
                if (k <= 99)  zbits |= (1u << u);
                if (k == 103) ebits |= (1u << u);             // blank slot -> ebS
            }
        }

#define STAGE_FAST(PAR, TB) do { \
    const float* src_ = lp + (size_t)(TB) * (B_DIM * V_DIM) + b * V_DIM; \
    float* dst_ = buf[PAR]; float* ebd_ = ebS[PAR]; \
    _Pragma("unroll") \
    for (int u = 0; u < LPER; ++u) { \
        float val_ = src_[woffs[u]]; \
        float ex_ = __builtin_amdgcn_exp2f(val_ * L2E); \
        dst_[doffs[u]] = ((zbits >> u) & 1u) ? ex_ : 0.0f; \
        if ((ebits >> u) & 1u) ebd_[tts[u]] = ex_; \
    } \
} while (0)

#define STAGE_SLOW(PAR, TB) do { \
    float* dst_ = buf[PAR]; float* ebd_ = ebS[PAR]; \
    _Pragma("unroll") \
    for (int u = 0; u < LPER; ++u) { \
        int t_ = (TB) + tts[u]; t_ = (t_ > T_DIM - 1) ? (T_DIM - 1) : t_; \
        int v_ = woffs[u] - tts[u] * (B_DIM * V_DIM); \
        float val_ = lp[((size_t)t_ * B_DIM + b) * V_DIM + v_]; \
        float ex_ = __builtin_amdgcn_exp2f(val_ * L2E); \
        dst_[doffs[u]] = ((zbits >> u) & 1u) ? ex_ : 0.0f; \
        if ((ebits >> u) & 1u) ebd_[tts[u]] = ex_; \
    } \
} while (0)

        if (wav != 0) STAGE_FAST(0, 1);    // stage chunk 0
        __syncthreads();   // B: buf0 ready

        // ------------- consumer macros -------------
#define PREF(bk, GG) do { \
    const float* rr_ = bufc + (GG) * (4 * ROWW) + offE; \
    e1g[bk][0] = rr_[0];          e3g[bk][0] = rr_[1]; \
    e1g[bk][1] = rr_[ROWW];       e3g[bk][1] = rr_[ROWW + 1]; \
    e1g[bk][2] = rr_[2 * ROWW];   e3g[bk][2] = rr_[2 * ROWW + 1]; \
    e1g[bk][3] = rr_[3 * ROWW];   e3g[bk][3] = rr_[3 * ROWW + 1]; \
    const float4 u_ = *(const float4*)(ebc + (GG) * 4); \
    ebg[bk][0] = u_.x; ebg[bk][1] = u_.y; ebg[bk][2] = u_.z; ebg[bk][3] = u_.w; \
} while (0)

// renorm lane max to [1,2); 2-level dead-lane exponent adoption; scale factors
// from POST-adoption left exponent (3 DPP shifts, all VALU-latency).
#define BD do { \
    float mz_ = fmaxf(fmaxf(p0, p1), fmaxf(p2, p3)); \
    int dead_ = (mz_ == 0.0f) ? 1 : 0; \
    int er_ = (int)((__float_as_uint(mz_) >> 23) & 255u); \
    unsigned fld_ = dead_ ? 127u : (unsigned)(254 - er_); \
    float sc_ = __uint_as_float(fld_ << 23); \
    p0 *= sc_; p1 *= sc_; p2 *= sc_; p3 *= sc_; \
    el += dead_ ? 0 : (er_ - 127); \
    int e1s_ = dpp_shr1_i(el); \
    int elA_ = dead_ ? e1s_ : el; \
    int e2s_ = dpp_shr1_i(elA_); \
    int elB_ = dead_ ? e2s_ : el; \
    int e3s_ = dpp_shr1_i(elB_); \
    int d1_ = e3s_ - elB_; d1_ = d1_ < -120 ? -120 : (d1_ > 120 ? 120 : d1_); \
    int d2_ = eLp  - elB_; d2_ = d2_ < -120 ? -120 : (d2_ > 120 ? 120 : d2_); \
    sfg = (l == 0) ? 0.0f : __uint_as_float((unsigned)(d1_ + 127) << 23); \
    sff = (l == 0) ? 0.0f : __uint_as_float((unsigned)(d2_ + 127) << 23); \
    el = elB_; eLp = e3s_; \
} while (0)

#define ST(SF, EB, E1, E3) do { \
    float h3_ = qv * (SF); \
    float vown_ = fmaf(cs3f, p1, p2 + p3); \
    float n3_ = vown_ * (E3); \
    float n0_ = (p0 + h3_) * (EB); \
    float n1_ = fmaf(cs1f, h3_, p0 + p1) * (E1); \
    float n2_ = (p1 + p2) * (EB); \
    qv = dpp_shr1_f(n3_); \
    p0 = n0_; p1 = n1_; p2 = n2_; p3 = n3_; \
} while (0)

#define GRP(bk) do { \
    BD; \
    ST(sff, ebg[bk][0], e1g[bk][0], e3g[bk][0]); \
    ST(sfg, ebg[bk][1], e1g[bk][1], e3g[bk][1]); \
    ST(sfg, ebg[bk][2], e1g[bk][2], e3g[bk][2]); \
    ST(sfg, ebg[bk][3], e1g[bk][3], e3g[bk][3]); \
} while (0)

#define GRPT(bk, BASE) do { \
    if ((BASE) < nst) { \
        BD; \
        ST(sff, ebg[bk][0], e1g[bk][0], e3g[bk][0]); \
        if ((BASE) + 1 < nst) ST(sfg, ebg[bk][1], e1g[bk][1], e3g[bk][1]); \
        if ((BASE) + 2 < nst) ST(sfg, ebg[bk][2], e1g[bk][2], e3g[bk][2]); \
        if ((BASE) + 3 < nst) ST(sfg, ebg[bk][3], e1g[bk][3], e3g[bk][3]); \
    } \
} while (0)

        for (int c = 0; c < NC; ++c) {
            if (wav == 0) {
                const float* bufc = buf[c & 1];
                const float* ebc  = ebS[c & 1];
                if (c < NCfull) {
                    PREF(0, 0); PREF(1, 1);
                    for (int gp = 0; gp < 5; ++gp) {
                        GRP(0); PREF(0, 2 * gp + 2);
                        GRP(1); PREF(1, 2 * gp + 3);
                    }
                    GRP(0); GRP(1);
                } else {
                    const int nst = tail;
                    PREF(0, 0); PREF(1, 1);
                    for (int gp = 0; gp < 5; ++gp) {
                        GRPT(0, 8 * gp);     PREF(0, 2 * gp + 2);
                        GRPT(1, 8 * gp + 4); PREF(1, 2 * gp + 3);
                    }
                    GRPT(0, 40); GRPT(1, 44);
                }
            } else if (c + 1 < NC) {
                const int cc = c + 1;
                const int tb = 1 + cc * CHUNK;
                if (tb + CHUNK <= T_DIM) {
                    if (cc & 1) STAGE_FAST(1, tb); else STAGE_FAST(0, tb);
                } else {
                    if (cc & 1) STAGE_SLOW(1, tb); else STAGE_SLOW(0, tb);
                }
            }
            __syncthreads();
        }

        if (wav == 0) {
            // extract alpha[2*tl] and alpha[2*tl-1]  (log2 domain via p, el)
            int idx = 2 * tl;
            int lanehi = idx >> 2, rhi = idx & 3;
            int lanelo = (idx - 1) >> 2, rlo = (idx - 1) & 3;
            float q0 = __shfl(p0, lanehi, 64), q1 = __shfl(p1, lanehi, 64);
            float q2 = __shfl(p2, lanehi, 64), q3 = __shfl(p3, lanehi, 64);
            int   eh = __shfl(el, lanehi, 64);
            float ph = (rhi == 0) ? q0 : (rhi == 1) ? q1 : (rhi == 2) ? q2 : q3;
            float g0 = __shfl(p0, lanelo, 64), g1 = __shfl(p1, lanelo, 64);
            float g2 = __shfl(p2, lanelo, 64), g3 = __shfl(p3, lanelo, 64);
            int   eo = __shfl(el, lanelo, 64);
            float pl = (rlo == 0) ? g0 : (rlo == 1) ? g1 : (rlo == 2) ? g2 : g3;
            float vhi = (ph > 0.0f) ? __builtin_amdgcn_logf(ph) + (float)eh : -3.0e9f;
            float vlo = (pl > 0.0f) ? __builtin_amdgcn_logf(pl) + (float)eo : -3.0e9f;
            float m = fmaxf(vhi, vlo);
            float d = fminf(vhi, vlo) - m;
            float ll2 = m + __builtin_amdgcn_logf(1.0f + __builtin_amdgcn_exp2f(d));
            float nll = -ll2 * LN2;
            if (!(nll < 1e9f)) nll = 0.0f;   // zero_infinity (NaN-safe)

            int last = 0;
            if (l == 0) {
                nlls[b] = nll;
                __threadfence();
                unsigned old = __hip_atomic_fetch_add(cnt, 1u, __ATOMIC_ACQ_REL,
                                                      __HIP_MEMORY_SCOPE_AGENT);
                last = (old == GRID_TOT - 1) ? 1 : 0;
            }
            last = __shfl(last, 0, 64);
            if (last) combine(l, partials, nlls, tlen, out);
        }
        return;
    }

    // ---------------- label-smoothing sum: grid-stride float4 reduction ----------------
    const int rb = bid - B_DIM;
    const float4* lp4 = (const float4*)lp;
    const int n4 = (T_DIM * B_DIM * V_DIM) / 4;
    const int NT = NRED * BLK;
    float s = 0.0f;
    for (int i = rb * BLK + tid; i < n4; i += NT) {
        float4 v = lp4[i];
        s += (v.x + v.y) + (v.z + v.w);
    }
    for (int off = 32; off; off >>= 1) s += __shfl_down(s, off, 64);
    if ((tid & 63) == 0) red[tid >> 6] = s;
    __syncthreads();
    int last = 0;
    if (tid == 0) {
        float total = ((red[0] + red[1]) + (red[2] + red[3]))
                    + ((red[4] + red[5]) + (red[6] + red[7]));
        partials[rb] = total;
        __threadfence();
        unsigned old = __hip_atomic_fetch_add(cnt, 1u, __ATOMIC_ACQ_REL,
                                              __HIP_MEMORY_SCOPE_AGENT);
        last = (old == GRID_TOT - 1) ? 1 : 0;
    }
    if (tid < 64) {
        last = __shfl(last, 0, 64);
        if (last) combine(tid, partials, nlls, tlen, out);
    }
}

extern "C" void kernel_launch(void* const* d_in, const int* in_sizes, int n_in,
                              void* d_out, int out_size, void* d_ws, size_t ws_size,
                              hipStream_t stream) {
    const float* lp  = (const float*)d_in[0];
    const int* tgt   = (const int*)d_in[1];
    const int* ilen  = (const int*)d_in[2];
    const int* tlen  = (const int*)d_in[3];
    float* out = (float*)d_out;
    float* ws  = (float*)d_ws;
    hipMemsetAsync(d_ws, 0, 4, stream);
    ctc_main<<<GRID_TOT, BLK, 0, stream>>>(lp, tgt, ilen, tlen, ws, out);
}

// Round 8
// 106.810 us; speedup vs baseline: 1.8284x; 1.3297x over previous
//
#include <hip/hip_runtime.h>
#include <hip/hip_bf16.h>

#define T_DIM 800
#define B_DIM 32
#define V_DIM 1024
#define S_DIM 100
#define L2E  1.4426950408889634f
#define LN2  0.6931471805599453f

#define NE   1600                /* E-precompute blocks: 4 waves x 4 rows = 16 rows each */
#define NRED 1504                /* reduction blocks */
#define EOFF 4096                /* E starts at ws + EOFF floats (16 KB) */
#define EROW 128                 /* padded row: 104 used slots */

// ws layout (32-bit slots):
// [0]                  : uint counter (zeroed by hipMemsetAsync each call)
// [1 .. 1+NRED)        : float partial sums (smoothing reduction)
// [1+NRED .. 1+NRED+32): float per-batch nll
// [EOFF ..)            : E[32][800][128] emission matrix (13.1 MB)

__device__ __forceinline__ float dpp_shr1_f(float x) {
    return __int_as_float(__builtin_amdgcn_update_dpp(
        0, __float_as_int(x), 0x138, 0xF, 0xF, false));
}
__device__ __forceinline__ int dpp_shr1_i(int x) {
    return __builtin_amdgcn_update_dpp(0, x, 0x138, 0xF, 0xF, false);
}
__device__ __forceinline__ float rl50(float x) {
    return __int_as_float(__builtin_amdgcn_readlane(__float_as_int(x), 50));
}

// ================= K1: E-precompute + smoothing reduction =================
extern "C" __global__ void __launch_bounds__(256)
ctc_prep(const float* __restrict__ lp,
         const int* __restrict__ tgt,
         float* __restrict__ ws)
{
    const int bid = blockIdx.x;
    const int tid = threadIdx.x;
    float* E = ws + EOFF;
    float* partials = ws + 1;

    if (bid < NE) {
        // ---- E rows: wave w handles rows 4w..4w+3 (same b: 4 | 800) ----
        const int wid = (bid << 2) + (tid >> 6);
        const int j   = tid & 63;
        const int row0 = wid << 2;
        const int b  = row0 / 800;
        const int t0 = row0 - b * 800;
        const int* tg = tgt + b * S_DIM;
        const int jj = j + 64;
        const int col1 = tg[j];                         // slots 0..63 = labels 0..63
        const int col2 = (jj < 100) ? tg[jj] : 0;       // slots 64..99 labels, 100..101 blank
        const bool z2 = (jj <= 101);
        const float* base = lp + (size_t)t0 * (B_DIM * V_DIM) + b * V_DIM;
        #pragma unroll
        for (int r = 0; r < 4; ++r) {
            const float* src = base + (size_t)r * (B_DIM * V_DIM);
            float v1 = src[col1];
            float v2 = src[col2];
            float e1 = __builtin_amdgcn_exp2f(v1 * L2E);
            float e2 = z2 ? __builtin_amdgcn_exp2f(v2 * L2E) : 0.0f;
            float* dst = E + (size_t)(row0 + r) * EROW;
            dst[j]  = e1;
            dst[jj] = e2;
        }
        return;
    }

    // ---- label-smoothing partial sums ----
    __shared__ float red[4];
    const int rb = bid - NE;
    const float4* lp4 = (const float4*)lp;
    const int n4 = (T_DIM * B_DIM * V_DIM) / 4;
    const int NT = NRED * 256;
    float s = 0.0f;
    for (int i = rb * 256 + tid; i < n4; i += NT) {
        float4 v = lp4[i];
        s += (v.x + v.y) + (v.z + v.w);
    }
    for (int off = 32; off; off >>= 1) s += __shfl_down(s, off, 64);
    if ((tid & 63) == 0) red[tid >> 6] = s;
    __syncthreads();
    if (tid == 0) partials[rb] = (red[0] + red[1]) + (red[2] + red[3]);
}

// ================= K2: recursion (1 wave/block, no barriers) =================
extern "C" __global__ void __launch_bounds__(64)
ctc_rec(const int* __restrict__ tgt,
        const int* __restrict__ ilen,
        const int* __restrict__ tlen,
        float* __restrict__ ws,
        float* __restrict__ out)
{
    unsigned int* cnt = (unsigned int*)ws;
    float* partials = ws + 1;
    float* nlls = ws + 1 + NRED;
    const int b = blockIdx.x;
    const int l = threadIdx.x;
    const float* E = ws + EOFF + (size_t)b * 800 * EROW;
    const int* tg = tgt + b * S_DIM;
    const int len = ilen[b];
    const int tl  = tlen[b];
    const int steps = len - 1;          // t = 1..len-1 ; len in [400,800]

    // skip-transition flags (lane l owns extended states 4l..4l+3)
    float cs1f = 0, cs3f = 0;
    if (l <= 49) {
        int v1 = tg[2 * l];
        int vp = (l >= 1) ? tg[2 * l - 1] : -1;
        cs1f = (v1 != vp) ? 1.0f : 0.0f;
        int v3 = tg[2 * l + 1];
        cs3f = (v3 != v1) ? 1.0f : 0.0f;
    }

    // t=0 init from E row 0: lane l's float2 = slots (2l, 2l+1); blank = lane50.x
    float p0 = 0, p1 = 0, p2 = 0, p3 = 0;
    float qv = 0, sff = 0, sfg = 0;
    int   el = 0, eLp = 0;
    {
        float2 q0 = ((const float2*)E)[l];
        float eb0 = rl50(q0.x);
        p0 = (l == 0) ? eb0  : 0.0f;
        p1 = (l == 0) ? q0.x : 0.0f;
    }

    // 4-bank register prefetch of 4-step groups (group g = steps 1+4g .. 4+4g)
    float2 eq[4][4];
#define PREFG(bk, G) do { \
    int tb_ = 1 + 4 * (G); \
    _Pragma("unroll") \
    for (int i_ = 0; i_ < 4; ++i_) { \
        int tc_ = tb_ + i_; tc_ = (tc_ > T_DIM - 1) ? (T_DIM - 1) : tc_; \
        eq[bk][i_] = ((const float2*)(E + (size_t)tc_ * EROW))[l]; \
    } \
} while (0)

// renorm lane max to [1,2); 2-level dead-lane exponent adoption; scale factors
// from POST-adoption left exponent (validated R6/R7 protocol).
#define BD do { \
    float mz_ = fmaxf(fmaxf(p0, p1), fmaxf(p2, p3)); \
    int dead_ = (mz_ == 0.0f) ? 1 : 0; \
    int er_ = (int)((__float_as_uint(mz_) >> 23) & 255u); \
    unsigned fld_ = dead_ ? 127u : (unsigned)(254 - er_); \
    float sc_ = __uint_as_float(fld_ << 23); \
    p0 *= sc_; p1 *= sc_; p2 *= sc_; p3 *= sc_; \
    el += dead_ ? 0 : (er_ - 127); \
    int e1s_ = dpp_shr1_i(el); \
    int elA_ = dead_ ? e1s_ : el; \
    int e2s_ = dpp_shr1_i(elA_); \
    int elB_ = dead_ ? e2s_ : el; \
    int e3s_ = dpp_shr1_i(elB_); \
    int d1_ = e3s_ - elB_; d1_ = d1_ < -120 ? -120 : (d1_ > 120 ? 120 : d1_); \
    int d2_ = eLp  - elB_; d2_ = d2_ < -120 ? -120 : (d2_ > 120 ? 120 : d2_); \
    sfg = (l == 0) ? 0.0f : __uint_as_float((unsigned)(d1_ + 127) << 23); \
    sff = (l == 0) ? 0.0f : __uint_as_float((unsigned)(d2_ + 127) << 23); \
    el = elB_; eLp = e3s_; \
} while (0)

#define ST(SF, Q, EBS) do { \
    float h3_ = qv * (SF); \
    float vown_ = fmaf(cs3f, p1, p2 + p3); \
    float n3_ = vown_ * (Q).y; \
    float n0_ = (p0 + h3_) * (EBS); \
    float n1_ = fmaf(cs1f, h3_, p0 + p1) * (Q).x; \
    float n2_ = (p1 + p2) * (EBS); \
    qv = dpp_shr1_f(n3_); \
    p0 = n0_; p1 = n1_; p2 = n2_; p3 = n3_; \
} while (0)

#define GRP(bk) do { \
    BD; \
    ST(sff, eq[bk][0], rl50(eq[bk][0].x)); \
    ST(sfg, eq[bk][1], rl50(eq[bk][1].x)); \
    ST(sfg, eq[bk][2], rl50(eq[bk][2].x)); \
    ST(sfg, eq[bk][3], rl50(eq[bk][3].x)); \
} while (0)

#define GRPT(bk, BASE) do { \
    if ((BASE) < nst) { \
        BD; \
        ST(sff, eq[bk][0], rl50(eq[bk][0].x)); \
        if ((BASE) + 1 < nst) ST(sfg, eq[bk][1], rl50(eq[bk][1].x)); \
        if ((BASE) + 2 < nst) ST(sfg, eq[bk][2], rl50(eq[bk][2].x)); \
        if ((BASE) + 3 < nst) ST(sfg, eq[bk][3], rl50(eq[bk][3].x)); \
    } \
} while (0)

    PREFG(0, 0); PREFG(1, 1); PREFG(2, 2); PREFG(3, 3);
    const int nsb = steps >> 4;         // full 16-step superblocks (>= 24)
    for (int s = 0; s < nsb; ++s) {
        GRP(0); PREFG(0, 4 * s + 4);
        GRP(1); PREFG(1, 4 * s + 5);
        GRP(2); PREFG(2, 4 * s + 6);
        GRP(3); PREFG(3, 4 * s + 7);
    }
    {
        const int nst = steps & 15;     // 0..15 remaining steps
        GRPT(0, 0); GRPT(1, 4); GRPT(2, 8); GRPT(3, 12);
    }

    // extract alpha[2*tl] and alpha[2*tl-1]  (log2 domain via p, el)
    int idx = 2 * tl;
    int lanehi = idx >> 2, rhi = idx & 3;
    int lanelo = (idx - 1) >> 2, rlo = (idx - 1) & 3;
    float q0 = __shfl(p0, lanehi, 64), q1 = __shfl(p1, lanehi, 64);
    float q2 = __shfl(p2, lanehi, 64), q3 = __shfl(p3, lanehi, 64);
    int   eh = __shfl(el, lanehi, 64);
    float ph = (rhi == 0) ? q0 : (rhi == 1) ? q1 : (rhi == 2) ? q2 : q3;
    float g0 = __shfl(p0, lanelo, 64), g1 = __shfl(p1, lanelo, 64);
    float g2 = __shfl(p2, lanelo, 64), g3 = __shfl(p3, lanelo, 64);
    int   eo = __shfl(el, lanelo, 64);
    float pl = (rlo == 0) ? g0 : (rlo == 1) ? g1 : (rlo == 2) ? g2 : g3;
    float vhi = (ph > 0.0f) ? __builtin_amdgcn_logf(ph) + (float)eh : -3.0e9f;
    float vlo = (pl > 0.0f) ? __builtin_amdgcn_logf(pl) + (float)eo : -3.0e9f;
    float m = fmaxf(vhi, vlo);
    float d = fminf(vhi, vlo) - m;
    float ll2 = m + __builtin_amdgcn_logf(1.0f + __builtin_amdgcn_exp2f(d));
    float nll = -ll2 * LN2;
    if (!(nll < 1e9f)) nll = 0.0f;      // zero_infinity (NaN-safe)

    int last = 0;
    if (l == 0) {
        nlls[b] = nll;
        __threadfence();
        unsigned old = __hip_atomic_fetch_add(cnt, 1u, __ATOMIC_ACQ_REL,
                                              __HIP_MEMORY_SCOPE_AGENT);
        last = (old == B_DIM - 1) ? 1 : 0;
    }
    last = __shfl(last, 0, 64);
    if (last) {
        // deterministic final combine (partials written by K1, stream-ordered)
        float ps = 0.0f;
        for (int i = l; i < NRED; i += 64) ps += partials[i];
        for (int off = 32; off; off >>= 1) ps += __shfl_down(ps, off, 64);
        float cs = 0.0f;
        if (l < B_DIM) cs = nlls[l] / (float)tlen[l];
        for (int off = 32; off; off >>= 1) cs += __shfl_down(cs, off, 64);
        if (l == 0) {
            float smooth = -ps / (float)((long long)T_DIM * B_DIM * V_DIM);
            float ctc = cs / (float)B_DIM;
            out[0] = 0.9f * ctc + 0.1f * smooth;
        }
    }
}

extern "C" void kernel_launch(void* const* d_in, const int* in_sizes, int n_in,
                              void* d_out, int out_size, void* d_ws, size_t ws_size,
                              hipStream_t stream) {
    const float* lp  = (const float*)d_in[0];
    const int* tgt   = (const int*)d_in[1];
    const int* ilen  = (const int*)d_in[2];
    const int* tlen  = (const int*)d_in[3];
    float* out = (float*)d_out;
    float* ws  = (float*)d_ws;
    hipMemsetAsync(d_ws, 0, 4, stream);
    ctc_prep<<<NE + NRED, 256, 0, stream>>>(lp, tgt, ws);
    ctc_rec<<<B_DIM, 64, 0, stream>>>(tgt, ilen, tlen, ws, out);
}

// Round 9
// 90.036 us; speedup vs baseline: 2.1691x; 1.1863x over previous
//
#include <hip/hip_runtime.h>
#include <hip/hip_bf16.h>

#define T_DIM 800
#define B_DIM 32
#define V_DIM 1024
#define S_DIM 100
#define L2E  1.4426950408889634f
#define LN2  0.6931471805599453f

#define NB1  1600                /* K1 blocks: 16 rows each (25600 rows total) */
#define EOFF 4096                /* E starts at ws + EOFF floats (16 KB) */
#define EROW 128                 /* padded E row: 104 used slots */

// ws layout (32-bit slots):
// [0]                  : uint counter (zeroed by hipMemsetAsync each call)
// [1 .. 1+NB1)         : float partial sums (smoothing reduction)
// [1+NB1 .. 1+NB1+32)  : float per-batch nll
// [EOFF ..)            : E[32][800][128] emission matrix (13.1 MB)

__device__ __forceinline__ float dpp_shr1_f(float x) {
    return __int_as_float(__builtin_amdgcn_update_dpp(
        0, __float_as_int(x), 0x138, 0xF, 0xF, false));
}
__device__ __forceinline__ int dpp_shr1_i(int x) {
    return __builtin_amdgcn_update_dpp(0, x, 0x138, 0xF, 0xF, false);
}
__device__ __forceinline__ float rl50(float x) {
    return __int_as_float(__builtin_amdgcn_readlane(__float_as_int(x), 50));
}

// ========== K1: fused smoothing-reduction + LDS-gathered E build ==========
// Block owns 16 consecutive global rows r = 16*bid + i (r = b*800 + t).
// 16 | 800 so one b per block. Stream row coalesced -> LDS; wave 0 gathers
// the 104 extended-label columns from LDS and writes E row coalesced.
extern "C" __global__ void __launch_bounds__(256)
ctc_prep(const float* __restrict__ lp,
         const int* __restrict__ tgt,
         float* __restrict__ ws)
{
    __shared__ float rowbuf[2][V_DIM];
    __shared__ float red[4];
    float* E = ws + EOFF;
    float* partials = ws + 1;
    const int bid = blockIdx.x;
    const int tid = threadIdx.x;
    const int b  = bid / 50;            // 50 blocks per batch
    const int t0 = (bid - b * 50) * 16;
    const int* tg = tgt + b * S_DIM;

    float s = 0.0f;
    #pragma unroll 1
    for (int i = 0; i < 16; ++i) {
        const int t = t0 + i;
        const float4 v = ((const float4*)(lp + ((size_t)t * B_DIM + b) * V_DIM))[tid];
        s += (v.x + v.y) + (v.z + v.w);
        ((float4*)rowbuf[i & 1])[tid] = v;
        __syncthreads();
        if (tid < 64) {
            const float* rb = rowbuf[i & 1];
            const int m = tid;
            float a, c;
            if (m <= 49) {                       // slots 2m,2m+1 = labels 2m,2m+1
                int2 t2 = ((const int2*)tg)[m];
                a = __builtin_amdgcn_exp2f(rb[t2.x] * L2E);
                c = __builtin_amdgcn_exp2f(rb[t2.y] * L2E);
            } else if (m == 50) {                // slots 100,101 = blank
                float ebv = __builtin_amdgcn_exp2f(rb[0] * L2E);
                a = ebv; c = ebv;
            } else {                             // slots 102..127 = dead
                a = 0.0f; c = 0.0f;
            }
            ((float2*)(E + ((size_t)b * 800 + t) * EROW))[m] = make_float2(a, c);
        }
    }
    for (int off = 32; off; off >>= 1) s += __shfl_down(s, off, 64);
    if ((tid & 63) == 0) red[tid >> 6] = s;
    __syncthreads();
    if (tid == 0) partials[bid] = (red[0] + red[1]) + (red[2] + red[3]);
}

// ========== K2: recursion (1 wave/block, 8-bank / 32-step prefetch) ==========
extern "C" __global__ void __launch_bounds__(64)
ctc_rec(const int* __restrict__ tgt,
        const int* __restrict__ ilen,
        const int* __restrict__ tlen,
        float* __restrict__ ws,
        float* __restrict__ out)
{
    unsigned int* cnt = (unsigned int*)ws;
    float* partials = ws + 1;
    float* nlls = ws + 1 + NB1;
    const int b = blockIdx.x;
    const int l = threadIdx.x;
    const float* E = ws + EOFF + (size_t)b * 800 * EROW;
    const int* tg = tgt + b * S_DIM;
    const int len = ilen[b];
    const int tl  = tlen[b];
    const int steps = len - 1;          // t = 1..len-1 ; len in [400,800]

    // skip-transition flags (lane l owns extended states 4l..4l+3)
    float cs1f = 0, cs3f = 0;
    if (l <= 49) {
        int v1 = tg[2 * l];
        int vp = (l >= 1) ? tg[2 * l - 1] : -1;
        cs1f = (v1 != vp) ? 1.0f : 0.0f;
        int v3 = tg[2 * l + 1];
        cs3f = (v3 != v1) ? 1.0f : 0.0f;
    }

    // t=0 init from E row 0: lane l's float2 = slots (2l, 2l+1); blank = lane50.x
    float p0 = 0, p1 = 0, p2 = 0, p3 = 0;
    float qv = 0, sff = 0, sfg = 0;
    int   el = 0, eLp = 0;
    {
        float2 q0 = ((const float2*)E)[l];
        float eb0 = rl50(q0.x);
        p0 = (l == 0) ? eb0  : 0.0f;
        p1 = (l == 0) ? q0.x : 0.0f;
    }

    // 8-bank register prefetch of 4-step groups (group g = steps 1+4g .. 4+4g)
    float2 eq[8][4];
#define PREFG(bk, G) do { \
    int tb_ = 1 + 4 * (G); \
    _Pragma("unroll") \
    for (int i_ = 0; i_ < 4; ++i_) { \
        int tc_ = tb_ + i_; tc_ = (tc_ > T_DIM - 1) ? (T_DIM - 1) : tc_; \
        eq[bk][i_] = ((const float2*)(E + (size_t)tc_ * EROW))[l]; \
    } \
} while (0)

// renorm lane max to [1,2); 2-level dead-lane exponent adoption; scale factors
// from POST-adoption left exponent (validated R6/R7/R8 protocol).
#define BD do { \
    float mz_ = fmaxf(fmaxf(p0, p1), fmaxf(p2, p3)); \
    int dead_ = (mz_ == 0.0f) ? 1 : 0; \
    int er_ = (int)((__float_as_uint(mz_) >> 23) & 255u); \
    unsigned fld_ = dead_ ? 127u : (unsigned)(254 - er_); \
    float sc_ = __uint_as_float(fld_ << 23); \
    p0 *= sc_; p1 *= sc_; p2 *= sc_; p3 *= sc_; \
    el += dead_ ? 0 : (er_ - 127); \
    int e1s_ = dpp_shr1_i(el); \
    int elA_ = dead_ ? e1s_ : el; \
    int e2s_ = dpp_shr1_i(elA_); \
    int elB_ = dead_ ? e2s_ : el; \
    int e3s_ = dpp_shr1_i(elB_); \
    int d1_ = e3s_ - elB_; d1_ = d1_ < -120 ? -120 : (d1_ > 120 ? 120 : d1_); \
    int d2_ = eLp  - elB_; d2_ = d2_ < -120 ? -120 : (d2_ > 120 ? 120 : d2_); \
    sfg = (l == 0) ? 0.0f : __uint_as_float((unsigned)(d1_ + 127) << 23); \
    sff = (l == 0) ? 0.0f : __uint_as_float((unsigned)(d2_ + 127) << 23); \
    el = elB_; eLp = e3s_; \
} while (0)

#define ST(SF, Q, EBS) do { \
    float h3_ = qv * (SF); \
    float vown_ = fmaf(cs3f, p1, p2 + p3); \
    float n3_ = vown_ * (Q).y; \
    float n0_ = (p0 + h3_) * (EBS); \
    float n1_ = fmaf(cs1f, h3_, p0 + p1) * (Q).x; \
    float n2_ = (p1 + p2) * (EBS); \
    qv = dpp_shr1_f(n3_); \
    p0 = n0_; p1 = n1_; p2 = n2_; p3 = n3_; \
} while (0)

#define GRP(bk) do { \
    BD; \
    ST(sff, eq[bk][0], rl50(eq[bk][0].x)); \
    ST(sfg, eq[bk][1], rl50(eq[bk][1].x)); \
    ST(sfg, eq[bk][2], rl50(eq[bk][2].x)); \
    ST(sfg, eq[bk][3], rl50(eq[bk][3].x)); \
} while (0)

#define GRPT(bk, BASE) do { \
    if ((BASE) < nst) { \
        BD; \
        ST(sff, eq[bk][0], rl50(eq[bk][0].x)); \
        if ((BASE) + 1 < nst) ST(sfg, eq[bk][1], rl50(eq[bk][1].x)); \
        if ((BASE) + 2 < nst) ST(sfg, eq[bk][2], rl50(eq[bk][2].x)); \
        if ((BASE) + 3 < nst) ST(sfg, eq[bk][3], rl50(eq[bk][3].x)); \
    } \
} while (0)

    PREFG(0, 0); PREFG(1, 1); PREFG(2, 2); PREFG(3, 3);
    PREFG(4, 4); PREFG(5, 5); PREFG(6, 6); PREFG(7, 7);
    const int nsb = steps >> 5;         // full 32-step superblocks (>= 12)
    for (int s = 0; s < nsb; ++s) {
        GRP(0); PREFG(0, 8 * s + 8);
        GRP(1); PREFG(1, 8 * s + 9);
        GRP(2); PREFG(2, 8 * s + 10);
        GRP(3); PREFG(3, 8 * s + 11);
        GRP(4); PREFG(4, 8 * s + 12);
        GRP(5); PREFG(5, 8 * s + 13);
        GRP(6); PREFG(6, 8 * s + 14);
        GRP(7); PREFG(7, 8 * s + 15);
    }
    {
        const int nst = steps & 31;     // 0..31 remaining steps
        GRPT(0, 0);  GRPT(1, 4);  GRPT(2, 8);  GRPT(3, 12);
        GRPT(4, 16); GRPT(5, 20); GRPT(6, 24); GRPT(7, 28);
    }

    // extract alpha[2*tl] and alpha[2*tl-1]  (log2 domain via p, el)
    int idx = 2 * tl;
    int lanehi = idx >> 2, rhi = idx & 3;
    int lanelo = (idx - 1) >> 2, rlo = (idx - 1) & 3;
    float q0 = __shfl(p0, lanehi, 64), q1 = __shfl(p1, lanehi, 64);
    float q2 = __shfl(p2, lanehi, 64), q3 = __shfl(p3, lanehi, 64);
    int   eh = __shfl(el, lanehi, 64);
    float ph = (rhi == 0) ? q0 : (rhi == 1) ? q1 : (rhi == 2) ? q2 : q3;
    float g0 = __shfl(p0, lanelo, 64), g1 = __shfl(p1, lanelo, 64);
    float g2 = __shfl(p2, lanelo, 64), g3 = __shfl(p3, lanelo, 64);
    int   eo = __shfl(el, lanelo, 64);
    float pl = (rlo == 0) ? g0 : (rlo == 1) ? g1 : (rlo == 2) ? g2 : g3;
    float vhi = (ph > 0.0f) ? __builtin_amdgcn_logf(ph) + (float)eh : -3.0e9f;
    float vlo = (pl > 0.0f) ? __builtin_amdgcn_logf(pl) + (float)eo : -3.0e9f;
    float m = fmaxf(vhi, vlo);
    float d = fminf(vhi, vlo) - m;
    float ll2 = m + __builtin_amdgcn_logf(1.0f + __builtin_amdgcn_exp2f(d));
    float nll = -ll2 * LN2;
    if (!(nll < 1e9f)) nll = 0.0f;      // zero_infinity (NaN-safe)

    int last = 0;
    if (l == 0) {
        nlls[b] = nll;
        __threadfence();
        unsigned old = __hip_atomic_fetch_add(cnt, 1u, __ATOMIC_ACQ_REL,
                                              __HIP_MEMORY_SCOPE_AGENT);
        last = (old == B_DIM - 1) ? 1 : 0;
    }
    last = __shfl(last, 0, 64);
    if (last) {
        // deterministic final combine (partials written by K1, stream-ordered)
        float ps = 0.0f;
        for (int i = l; i < NB1; i += 64) ps += partials[i];
        for (int off = 32; off; off >>= 1) ps += __shfl_down(ps, off, 64);
        float cs = 0.0f;
        if (l < B_DIM) cs = nlls[l] / (float)tlen[l];
        for (int off = 32; off; off >>= 1) cs += __shfl_down(cs, off, 64);
        if (l == 0) {
            float smooth = -ps / (float)((long long)T_DIM * B_DIM * V_DIM);
            float ctc = cs / (float)B_DIM;
            out[0] = 0.9f * ctc + 0.1f * smooth;
        }
    }
}

extern "C" void kernel_launch(void* const* d_in, const int* in_sizes, int n_in,
                              void* d_out, int out_size, void* d_ws, size_t ws_size,
                              hipStream_t stream) {
    const float* lp  = (const float*)d_in[0];
    const int* tgt   = (const int*)d_in[1];
    const int* ilen  = (const int*)d_in[2];
    const int* tlen  = (const int*)d_in[3];
    float* out = (float*)d_out;
    float* ws  = (float*)d_ws;
    hipMemsetAsync(d_ws, 0, 4, stream);
    ctc_prep<<<NB1, 256, 0, stream>>>(lp, tgt, ws);
    ctc_rec<<<B_DIM, 64, 0, stream>>>(tgt, ilen, tlen, ws, out);
}